// Round 9
// baseline (228.194 us; speedup 1.0000x reference)
//
#include <hip/hip_runtime.h>

#define NT   256
#define HW   3136          // 56*56 = 64 lanes * 49 elements
#define KSEL 627u          // int(0.2 * 3136)
#define CAP  512           // candidate list capacity
#define T1B  0x3F933333u   // ~1.15f bits (seed bracket lo)
#define T2B  0x3FB9999Au   // ~1.45f bits (seed bracket hi)

typedef unsigned int u32;
typedef unsigned long long u64;

__device__ __forceinline__ u32 prefix_cnt(u64 m) {   // #set bits below this lane
    return __builtin_amdgcn_mbcnt_hi((u32)(m >> 32),
           __builtin_amdgcn_mbcnt_lo((u32)m, 0u));
}

// Process one row held entirely in registers (a[12] uint4 + tail tvu).
// Finds the exact top-k threshold (TK, CO) and stores the masked row.
__device__ __forceinline__ void do_row(const uint4 (&a)[12], const u32 tvu,
                                       u32* __restrict__ Lk, u32* __restrict__ Li,
                                       const int lane, float* __restrict__ orow) {
    uint4* orwu = (uint4*)orow;

    // ---- seed scan: counts at T1,T2 + compact band [T1,T2) to LDS (no atomics)
    u32 c1 = 0, c2 = 0, base = 0;
#define PROCA(U, IDX)                                                          \
    { const u32 _k = (U) & 0x7fffffffu;                                        \
      const u64 m1 = __ballot(_k >= T1B);                                      \
      const u64 m2 = __ballot(_k >= T2B);                                      \
      c1 += (u32)__popcll(m1); c2 += (u32)__popcll(m2);                        \
      const u64 mb = m1 & ~m2;                                                 \
      if ((mb >> lane) & 1ull) {                                               \
          const u32 off = base + prefix_cnt(mb);                               \
          Lk[off] = _k; Li[off] = (IDX); }                                     \
      base += (u32)__popcll(mb); }
#pragma unroll
    for (int j = 0; j < 12; ++j) {
        const u32 bi = (u32)(lane << 2) + (u32)(j << 8);
        PROCA(a[j].x, bi + 0u) PROCA(a[j].y, bi + 1u)
        PROCA(a[j].z, bi + 2u) PROCA(a[j].w, bi + 3u)
    }
    PROCA(tvu, 3072u + (u32)lane)
#undef PROCA

    // ---- bracket [lo,hi): cnt(>=lo) >= k > cnt(>=hi), list holds keys in [lo,hi)
    u32 lo, hi, chi, Lc;
    bool degen = false;
    if ((c1 >= KSEL) && (KSEL > c2) && ((c1 - c2) <= CAP)) {
        lo = T1B; hi = T2B; chi = c2; Lc = c1 - c2;     // seed list already valid
    } else {
        // rare general path: key-space bisection on registers
        u32 clo;
        lo = 0u; clo = HW; hi = 0x80000000u; chi = 0u;
        if (c1 >= KSEL) {
            lo = T1B; clo = c1;
            if (c2 >= KSEL) { lo = T2B; clo = c2; }
            else            { hi = T2B; chi = c2; }
        } else { hi = T1B; chi = c1; }
        while (clo - chi > CAP && hi - lo > 1u) {
            const u32 mid = lo + ((hi - lo) >> 1);
            u32 c = 0;
#pragma unroll
            for (int j = 0; j < 12; ++j) {
                c += (u32)__popcll(__ballot((a[j].x & 0x7fffffffu) >= mid));
                c += (u32)__popcll(__ballot((a[j].y & 0x7fffffffu) >= mid));
                c += (u32)__popcll(__ballot((a[j].z & 0x7fffffffu) >= mid));
                c += (u32)__popcll(__ballot((a[j].w & 0x7fffffffu) >= mid));
            }
            c += (u32)__popcll(__ballot((tvu & 0x7fffffffu) >= mid));
            if (c >= KSEL) { lo = mid; clo = c; } else { hi = mid; chi = c; }
        }
        Lc = clo - chi;
        if (Lc <= CAP) {   // recompact list with final bracket
            base = 0;
#define PROCB(U, IDX)                                                          \
            { const u32 _k = (U) & 0x7fffffffu;                                \
              const u64 mb = __ballot(_k >= lo && _k < hi);                    \
              if ((mb >> lane) & 1ull) {                                       \
                  const u32 off = base + prefix_cnt(mb);                       \
                  Lk[off] = _k; Li[off] = (IDX); }                             \
              base += (u32)__popcll(mb); }
#pragma unroll
            for (int j = 0; j < 12; ++j) {
                const u32 bi = (u32)(lane << 2) + (u32)(j << 8);
                PROCB(a[j].x, bi + 0u) PROCB(a[j].y, bi + 1u)
                PROCB(a[j].z, bi + 2u) PROCB(a[j].w, bi + 3u)
            }
            PROCB(tvu, 3072u + (u32)lane)
#undef PROCB
        } else {
            degen = true;   // hi-lo==1 with >CAP duplicates of key 'lo'
        }
    }

    u32 TK = 0, CO = HW - 1u;
    if (degen) {
        // exact tie cutoff by index over registers (never on real data)
        TK = lo;
        const u32 rk = KSEL - chi;
        u32 lo3 = 0u, hi3 = HW - 1u;
        while (lo3 < hi3) {
            const u32 mid = (lo3 + hi3) >> 1;
            u32 c = 0;
#pragma unroll
            for (int j = 0; j < 12; ++j) {
                const u32 bi = (u32)(lane << 2) + (u32)(j << 8);
                c += (u32)__popcll(__ballot(((a[j].x & 0x7fffffffu) == TK) && (bi + 0u) <= mid));
                c += (u32)__popcll(__ballot(((a[j].y & 0x7fffffffu) == TK) && (bi + 1u) <= mid));
                c += (u32)__popcll(__ballot(((a[j].z & 0x7fffffffu) == TK) && (bi + 2u) <= mid));
                c += (u32)__popcll(__ballot(((a[j].w & 0x7fffffffu) == TK) && (bi + 3u) <= mid));
            }
            c += (u32)__popcll(__ballot(((tvu & 0x7fffffffu) == TK) && (3072u + (u32)lane) <= mid));
            if (c >= rk) hi3 = mid; else lo3 = mid + 1u;
        }
        CO = lo3;
    } else {
        // ---- finisher on the LDS list (wave-local, no barriers)
        const u32 rk = KSEL - chi;       // 1 <= rk <= Lc
        u32 kk[8];
#pragma unroll
        for (int j2 = 0; j2 < 8; ++j2) {
            const u32 s = (u32)lane + (u32)(j2 << 6);
            kk[j2] = (s < Lc) ? Lk[s] : 0u;   // pad 0: < any probe (probes >= 1)
        }
        u32 lo2 = lo, hi2 = hi;
        bool done = false;
        while (hi2 - lo2 > 1u) {
            const u32 mid = lo2 + ((hi2 - lo2) >> 1);
            u32 c = 0;
#pragma unroll
            for (int j2 = 0; j2 < 8; ++j2)
                c += (u32)__popcll(__ballot(kk[j2] >= mid));
            if (c == rk) {
                // exact hit: threshold = min candidate >= mid, keep all of them
                u32 mn = 0xffffffffu;
#pragma unroll
                for (int j2 = 0; j2 < 8; ++j2) {
                    const u32 t = (kk[j2] >= mid) ? kk[j2] : 0xffffffffu;
                    mn = mn < t ? mn : t;
                }
#pragma unroll
                for (int o = 32; o >= 1; o >>= 1) {
                    const u32 t = (u32)__shfl_xor((int)mn, o, 64);
                    mn = mn < t ? mn : t;
                }
                TK = mn; done = true; break;
            }
            if (c > rk) lo2 = mid; else hi2 = mid;
        }
        if (!done) {
            TK = lo2;
            u32 cgt = 0;
#pragma unroll
            for (int j2 = 0; j2 < 8; ++j2)
                cgt += (u32)__popcll(__ballot(kk[j2] > TK));
            const u32 r = rk - cgt;      // equals to keep, >= 1
            u64 eqm[8];
            u32 eqs = 0;
#pragma unroll
            for (int j2 = 0; j2 < 8; ++j2) {
                const u32 s = (u32)lane + (u32)(j2 << 6);
                eqm[j2] = __ballot(kk[j2] == TK && s < Lc);
                eqs += (u32)__popcll(eqm[j2]);
            }
            if (r != eqs) {
                // cold tie path: r-th smallest index among equals (all in list)
                u32 lo3 = 0u, hi3 = HW - 1u;
                while (lo3 < hi3) {
                    const u32 mid = (lo3 + hi3) >> 1;
                    u32 c = 0;
#pragma unroll
                    for (int j2 = 0; j2 < 8; ++j2) {
                        const u32 s = (u32)lane + (u32)(j2 << 6);
                        c += (u32)__popcll(eqm[j2] & __ballot(Li[s] <= mid));
                    }
                    if (c >= r) hi3 = mid; else lo3 = mid + 1u;
                }
                CO = lo3;
            }
        }
    }

    // ---- single store from registers (coalesced uint4)
    if (CO == HW - 1u) {   // dominant path: pure threshold (float cmp == int-key cmp)
        const float tkf = __uint_as_float(TK);
#pragma unroll
        for (int j = 0; j < 12; ++j) {
            uint4 o;
            o.x = (__builtin_fabsf(__uint_as_float(a[j].x)) >= tkf) ? a[j].x : 0u;
            o.y = (__builtin_fabsf(__uint_as_float(a[j].y)) >= tkf) ? a[j].y : 0u;
            o.z = (__builtin_fabsf(__uint_as_float(a[j].z)) >= tkf) ? a[j].z : 0u;
            o.w = (__builtin_fabsf(__uint_as_float(a[j].w)) >= tkf) ? a[j].w : 0u;
            orwu[lane + (j << 6)] = o;
        }
        orow[3072 + lane] = (__builtin_fabsf(__uint_as_float(tvu)) >= tkf)
                            ? __uint_as_float(tvu) : 0.0f;
    } else {
        // cold tie path: exact int compares with index cutoff
#define KEEPU(U, IDX) ((((U) & 0x7fffffffu) > TK ||                            \
                        (((U) & 0x7fffffffu) == TK && (IDX) <= CO)) ? (U) : 0u)
#pragma unroll
        for (int j = 0; j < 12; ++j) {
            const u32 bi = (u32)(lane << 2) + (u32)(j << 8);
            uint4 o;
            o.x = KEEPU(a[j].x, bi + 0u);
            o.y = KEEPU(a[j].y, bi + 1u);
            o.z = KEEPU(a[j].z, bi + 2u);
            o.w = KEEPU(a[j].w, bi + 3u);
            orwu[lane + (j << 6)] = o;
        }
        orow[3072 + lane] = __uint_as_float(KEEPU(tvu, 3072u + (u32)lane));
#undef KEEPU
    }
}

// Each wave handles 2 consecutive rows; row B's loads are issued up front so
// they are in flight during row A's compute/finisher/store (cross-row pipeline).
__global__ __launch_bounds__(NT, 4) void topk_mask_kernel(const float* __restrict__ x,
                                                          float* __restrict__ out) {
    __shared__ u32 LkA[8][CAP];
    __shared__ u32 LiA[8][CAP];

    const int tid  = threadIdx.x;
    const int wid  = tid >> 6;
    const int lane = tid & 63;
    const u32 rowA = blockIdx.x * 8u + (u32)wid * 2u;
    const u32 rowB = rowA + 1u;

    const float* xA  = x + (size_t)rowA * HW;
    const float* xB  = x + (size_t)rowB * HW;
    const uint4* xa4 = (const uint4*)xA;
    const uint4* xb4 = (const uint4*)xB;

    uint4 a[12], b[12];
#pragma unroll
    for (int j = 0; j < 12; ++j) a[j] = xa4[lane + (j << 6)];
    const u32 ta = __float_as_uint(xA[3072 + lane]);
#pragma unroll
    for (int j = 0; j < 12; ++j) b[j] = xb4[lane + (j << 6)];
    const u32 tb = __float_as_uint(xB[3072 + lane]);

    do_row(a, ta, LkA[wid * 2 + 0], LiA[wid * 2 + 0], lane, out + (size_t)rowA * HW);
    do_row(b, tb, LkA[wid * 2 + 1], LiA[wid * 2 + 1], lane, out + (size_t)rowB * HW);
}

extern "C" void kernel_launch(void* const* d_in, const int* in_sizes, int n_in,
                              void* d_out, int out_size, void* d_ws, size_t ws_size,
                              hipStream_t stream) {
    const float* x = (const float*)d_in[0];
    float* out = (float*)d_out;
    const int rows = in_sizes[0] / HW;       // 8192
    topk_mask_kernel<<<rows / 8, NT, 0, stream>>>(x, out);
}